// Round 2
// baseline (446.828 us; speedup 1.0000x reference)
//
#include <hip/hip_runtime.h>
#include <hip/hip_bf16.h>
#include <stdint.h>

typedef short bf16x8 __attribute__((ext_vector_type(8)));
typedef float f32x4 __attribute__((ext_vector_type(4)));
typedef unsigned short u16;
typedef unsigned short u16x4 __attribute__((ext_vector_type(4)));
typedef unsigned short u16x8 __attribute__((ext_vector_type(8)));

#define LOG2E 1.44269504088896f

// sizes
#define Bz 4
#define Sz 2048
#define Hz 1024
#define NHz 16
#define HDz 64

__device__ __forceinline__ u16 f2bf(float f) {
  uint32_t u = __builtin_bit_cast(uint32_t, f);
  u += 0x7fffu + ((u >> 16) & 1u);
  return (u16)(u >> 16);
}
__device__ __forceinline__ float bf2f(u16 h) {
  uint32_t u = ((uint32_t)h) << 16;
  return __builtin_bit_cast(float, u);
}
// RNE f32->bf16 via HIP intrinsic; compiler fuses pairs into v_cvt_pk_bf16_f32.
__device__ __forceinline__ u16 f2bfrn(float f) {
  return __builtin_bit_cast(u16, __float2bfloat16(f));
}

__device__ __forceinline__ void gll16(const void* g, void* l) {
  __builtin_amdgcn_global_load_lds((const __attribute__((address_space(1))) void*)g,
                                   (__attribute__((address_space(3))) void*)l,
                                   16, 0, 0);
}

// ---------------- X (f32) -> bf16 ----------------
__global__ void k_cvt_x(const float* __restrict__ X, u16* __restrict__ Xb) {
  int i = blockIdx.x * 256 + threadIdx.x;
  float4 v = ((const float4*)X)[i];
  u16x4 r;
  r[0] = f2bf(v.x); r[1] = f2bf(v.y); r[2] = f2bf(v.z); r[3] = f2bf(v.w);
  ((u16x4*)Xb)[i] = r;
}

// ------- pack & transpose [Wq|Wk|Wv|Ws] -> Wt[3200][1024] bf16 -------
__global__ void k_cvt_w(const float* __restrict__ Wq, const float* __restrict__ Wk,
                        const float* __restrict__ Wv, const float* __restrict__ Ws,
                        u16* __restrict__ Wt) {
  __shared__ float tile[64][65];
  int n0 = blockIdx.x * 64, k0 = blockIdx.y * 64;
  const float* src; int ld, c0;
  if (n0 < 1024)      { src = Wq; ld = 1024; c0 = n0; }
  else if (n0 < 2048) { src = Wk; ld = 1024; c0 = n0 - 1024; }
  else if (n0 < 3072) { src = Wv; ld = 1024; c0 = n0 - 2048; }
  else                { src = Ws; ld = 128;  c0 = n0 - 3072; }
  int t = threadIdx.x;
  #pragma unroll
  for (int i = 0; i < 16; ++i) {
    int idx = t + i * 256; int r = idx >> 6, c = idx & 63;
    tile[r][c] = src[(size_t)(k0 + r) * ld + c0 + c];
  }
  __syncthreads();
  #pragma unroll
  for (int i = 0; i < 16; ++i) {
    int idx = t + i * 256; int rn = idx >> 6, ck = idx & 63;
    Wt[(size_t)(n0 + rn) * 1024 + k0 + ck] = f2bf(tile[ck][rn]);
  }
}

// ---------------- fused QKV+S GEMM: [8192,1024] x [1024,3200] ----------------
__launch_bounds__(256)
__global__ void k_gemm(const u16* __restrict__ Xb, const u16* __restrict__ Wt,
                       const float* __restrict__ bq, const float* __restrict__ bk,
                       const float* __restrict__ bv, const float* __restrict__ bs,
                       u16* __restrict__ Qw, u16* __restrict__ Kw, u16* __restrict__ Vw,
                       float* __restrict__ Sw) {
  __shared__ u16 As[128 * 32];
  __shared__ u16 Bs[128 * 32];
  int t = threadIdx.x, lane = t & 63;
  int wave = t >> 6, wr = wave >> 1, wc = wave & 1;
  int m0 = blockIdx.y * 128, n0 = blockIdx.x * 128;

  f32x4 acc[4][4];
  #pragma unroll
  for (int i = 0; i < 4; ++i)
    #pragma unroll
    for (int j = 0; j < 4; ++j) { f32x4 z = {0.f,0.f,0.f,0.f}; acc[i][j] = z; }

  int srow = t >> 2;
  int sobyte = (t & 3) << 4;

  for (int kt = 0; kt < 32; ++kt) {
    int kb = kt * 64;
    #pragma unroll
    for (int c = 0; c < 2; ++c) {
      int row = c * 64 + srow;
      int sb = sobyte ^ ((row & 3) << 4);
      gll16((const char*)(Xb + (size_t)(m0 + row) * 1024) + kb + sb,
            (char*)As + row * 64 + sobyte);
    }
    #pragma unroll
    for (int c = 0; c < 2; ++c) {
      int row = c * 64 + srow;
      int sb = sobyte ^ ((row & 3) << 4);
      gll16((const char*)(Wt + (size_t)(n0 + row) * 1024) + kb + sb,
            (char*)Bs + row * 64 + sobyte);
    }
    __syncthreads();
    bf16x8 af[4], bfr[4];
    #pragma unroll
    for (int ai = 0; ai < 4; ++ai) {
      int row = wr * 64 + ai * 16 + (lane & 15);
      int bo = row * 64 + ((((lane >> 4) << 4)) ^ ((row & 3) << 4));
      af[ai] = *(const bf16x8*)((const char*)As + bo);
    }
    #pragma unroll
    for (int bj = 0; bj < 4; ++bj) {
      int row = wc * 64 + bj * 16 + (lane & 15);
      int bo = row * 64 + ((((lane >> 4) << 4)) ^ ((row & 3) << 4));
      bfr[bj] = *(const bf16x8*)((const char*)Bs + bo);
    }
    #pragma unroll
    for (int ai = 0; ai < 4; ++ai)
      #pragma unroll
      for (int bj = 0; bj < 4; ++bj)
        acc[ai][bj] = __builtin_amdgcn_mfma_f32_16x16x32_bf16(af[ai], bfr[bj], acc[ai][bj], 0, 0, 0);
    __syncthreads();
  }

  #pragma unroll
  for (int ai = 0; ai < 4; ++ai) {
    #pragma unroll
    for (int bj = 0; bj < 4; ++bj) {
      #pragma unroll
      for (int r = 0; r < 4; ++r) {
        int m = m0 + wr * 64 + ai * 16 + ((lane >> 4) << 2) + r;
        int j = n0 + wc * 64 + bj * 16 + (lane & 15);
        float v = acc[ai][bj][r];
        int b = m >> 11, si = m & 2047;
        if (j < 3072) {
          float bias = (j < 1024) ? bq[j] : (j < 2048) ? bk[j - 1024] : bv[j - 2048];
          v += bias;
          int jj = j & 1023, h = jj >> 6, d = jj & 63;
          size_t dst = (((size_t)(b * NHz + h) * Sz + si) << 6) + d;
          u16 hv = f2bf(v);
          if (j < 1024) Qw[dst] = hv;
          else if (j < 2048) Kw[dst] = hv;
          else Vw[dst] = hv;
        } else {
          int c = j - 3072;
          v += bs[c];
          float sig = 1.0f / (1.0f + __expf(-v));
          // fold softmax 1/sqrt(64) AND log2(e) (exp->exp2 domain) into Q scale
          Sw[(size_t)m * 128 + c] = (0.9f + 0.2f * sig) * 0.125f * LOG2E;
        }
      }
    }
  }
}

// ---------------- Q *= s (per head,group); s includes 0.125*log2e ----------------
__global__ void k_scale_q(u16* __restrict__ Qw, const float* __restrict__ Sw) {
  int tid = blockIdx.x * 256 + threadIdx.x;
  size_t base = (size_t)tid * 8;
  int bh = (int)(base >> 17);
  int si = (int)((base >> 6) & 2047);
  int d0 = (int)(base & 63);
  int b = bh >> 4, h = bh & 15;
  float s = Sw[((size_t)(b * Sz + si)) * 128 + h * 8 + (d0 >> 3)];
  u16x8 v = *(u16x8*)(Qw + base);
  #pragma unroll
  for (int j = 0; j < 8; ++j) v[j] = f2bf(bf2f(v[j]) * s);
  *(u16x8*)(Qw + base) = v;
}

// ---------------- V [bh][s][d] -> Vt [bh][d][s] ----------------
__global__ void k_trans_v(const u16* __restrict__ Vw, u16* __restrict__ Vt) {
  __shared__ u16 tile[64][65];
  int bh = blockIdx.y, s0 = blockIdx.x * 64;
  int t = threadIdx.x;
  const u16* src = Vw + ((size_t)bh * Sz + s0) * 64;
  #pragma unroll
  for (int i = 0; i < 16; ++i) {
    int idx = t + i * 256; int r = idx >> 6, c = idx & 63;
    tile[r][c] = src[r * 64 + c];
  }
  __syncthreads();
  u16* dst = Vt + (size_t)bh * 64 * Sz;
  #pragma unroll
  for (int i = 0; i < 16; ++i) {
    int idx = t + i * 256; int d = idx >> 6, ss = idx & 63;
    dst[(size_t)d * Sz + s0 + ss] = tile[ss][d];
  }
}

// ---------------- attention: no K/V staging, no barriers, no max ----------------
// grid (16 q-blocks of 128, 64 bh); 4 waves x 32 q-rows; KVBLK=64.
// Swapped QK^T: mfma(K,Q) -> lane holds P[kv slice][q=lane&15]; exp2 in-lane;
// P relayout via wave-private swizzled LDS; l-sum reduced once at the end.
__launch_bounds__(256)
__global__ void k_attn(const u16* __restrict__ Qw, const u16* __restrict__ Kw,
                       const u16* __restrict__ Vt, float* __restrict__ out) {
  __shared__ u16 Pl[4][32 * 64];   // per-wave P, XOR-swizzled rows (128B)

  int t = threadIdx.x, lane = t & 63, wave = t >> 6;
  int l15 = lane & 15, g = lane >> 4;
  int bh = blockIdx.y, b = bh >> 4, h = bh & 15;
  int q0 = blockIdx.x * 128 + wave * 32;

  const u16* Qb = Qw + (size_t)bh * Sz * 64;
  const char* Kg = (const char*)(Kw + (size_t)bh * Sz * 64);
  const char* Vg = (const char*)(Vt + (size_t)bh * 64 * Sz);
  u16* Pw = Pl[wave];
  int sw = (l15 & 7) << 4;

  // Q fragments: [qi][ks], row q0+16qi+l15, d = 32ks + 8g .. +7  (already scaled)
  bf16x8 qf[2][2];
  #pragma unroll
  for (int qi = 0; qi < 2; ++qi)
    #pragma unroll
    for (int ks = 0; ks < 2; ++ks)
      qf[qi][ks] = *(const bf16x8*)(Qb + (size_t)(q0 + 16 * qi + l15) * 64 + 32 * ks + 8 * g);

  f32x4 o[2][4];
  #pragma unroll
  for (int qi = 0; qi < 2; ++qi)
    #pragma unroll
    for (int nt = 0; nt < 4; ++nt) { f32x4 z = {0.f,0.f,0.f,0.f}; o[qi][nt] = z; }
  float lsum[2] = {0.f, 0.f};

  for (int kv0 = 0; kv0 < Sz; kv0 += 64) {
    // ---- QK^T (swapped) ----
    f32x4 sc[2][4];
    #pragma unroll
    for (int nt = 0; nt < 4; ++nt) {
      const char* kr = Kg + (size_t)(kv0 + 16 * nt + l15) * 128 + 16 * g;
      bf16x8 kf0 = *(const bf16x8*)kr;
      bf16x8 kf1 = *(const bf16x8*)(kr + 64);
      #pragma unroll
      for (int qi = 0; qi < 2; ++qi) {
        f32x4 a = {0.f,0.f,0.f,0.f};
        a = __builtin_amdgcn_mfma_f32_16x16x32_bf16(kf0, qf[qi][0], a, 0, 0, 0);
        a = __builtin_amdgcn_mfma_f32_16x16x32_bf16(kf1, qf[qi][1], a, 0, 0, 0);
        sc[qi][nt] = a;
      }
    }
    // ---- p = exp2(S'), accumulate l, pack P -> wave-private LDS ----
    #pragma unroll
    for (int qi = 0; qi < 2; ++qi) {
      int rbase = (16 * qi + l15) * 128;
      #pragma unroll
      for (int nt = 0; nt < 4; ++nt) {
        float p0 = __builtin_amdgcn_exp2f(sc[qi][nt][0]);
        float p1 = __builtin_amdgcn_exp2f(sc[qi][nt][1]);
        float p2 = __builtin_amdgcn_exp2f(sc[qi][nt][2]);
        float p3 = __builtin_amdgcn_exp2f(sc[qi][nt][3]);
        lsum[qi] += (p0 + p1) + (p2 + p3);
        u16x4 pk;
        pk[0] = f2bfrn(p0); pk[1] = f2bfrn(p1);
        pk[2] = f2bfrn(p2); pk[3] = f2bfrn(p3);
        *(u16x4*)((char*)Pw + rbase + ((32 * nt + 8 * g) ^ sw)) = pk;
      }
    }
    // ---- PV: O[q][d] += P @ V ----
    #pragma unroll
    for (int ks = 0; ks < 2; ++ks) {
      bf16x8 pa[2];
      #pragma unroll
      for (int qi = 0; qi < 2; ++qi)
        pa[qi] = *(const bf16x8*)((char*)Pw + (16 * qi + l15) * 128 + ((64 * ks + 16 * g) ^ sw));
      #pragma unroll
      for (int nt = 0; nt < 4; ++nt) {
        bf16x8 vf = *(const bf16x8*)(Vg + (size_t)(16 * nt + l15) * (Sz * 2) +
                                     (size_t)(kv0 + 32 * ks + 8 * g) * 2);
        o[0][nt] = __builtin_amdgcn_mfma_f32_16x16x32_bf16(pa[0], vf, o[0][nt], 0, 0, 0);
        o[1][nt] = __builtin_amdgcn_mfma_f32_16x16x32_bf16(pa[1], vf, o[1][nt], 0, 0, 0);
      }
    }
  }

  // ---- final l reduction across the 4 lane-groups, then write ----
  #pragma unroll
  for (int qi = 0; qi < 2; ++qi) {
    float l = lsum[qi];
    l += __shfl_xor(l, 16);
    l += __shfl_xor(l, 32);
    lsum[qi] = 1.0f / l;
  }
  #pragma unroll
  for (int qi = 0; qi < 2; ++qi) {
    float li[4];
    #pragma unroll
    for (int r = 0; r < 4; ++r) li[r] = __shfl(lsum[qi], 4 * g + r);
    #pragma unroll
    for (int nt = 0; nt < 4; ++nt)
      #pragma unroll
      for (int r = 0; r < 4; ++r)
        out[((size_t)(b * Sz + q0 + 16 * qi + 4 * g + r)) * (NHz * HDz) +
            h * 64 + 16 * nt + l15] = o[qi][nt][r] * li[r];
  }
}

extern "C" void kernel_launch(void* const* d_in, const int* in_sizes, int n_in,
                              void* d_out, int out_size, void* d_ws, size_t ws_size,
                              hipStream_t stream) {
  const float* X  = (const float*)d_in[0];
  const float* Wq = (const float*)d_in[1];
  const float* bq = (const float*)d_in[2];
  const float* Wk = (const float*)d_in[3];
  const float* bk = (const float*)d_in[4];
  const float* Wv = (const float*)d_in[5];
  const float* bv = (const float*)d_in[6];
  const float* Ws = (const float*)d_in[7];
  const float* bs = (const float*)d_in[8];
  float* out = (float*)d_out;

  // ws: Qw | Kw | Vw | Vt  (16 MB each)
  char* ws = (char*)d_ws;
  u16* Qw = (u16*)(ws);
  u16* Kw = (u16*)(ws + (size_t)(16u << 20));
  u16* Vw = (u16*)(ws + (size_t)(32u << 20));
  u16* Vt = (u16*)(ws + (size_t)(48u << 20));

  // d_out doubles as scratch: Xb (16MB) | Wt (6.55MB) | Sw (4MB); all consumed
  // before k_attn overwrites the output.
  char* ob = (char*)d_out;
  u16* Xb   = (u16*)ob;
  u16* Wt   = (u16*)(ob + (size_t)(16u << 20));
  float* Sw = (float*)(ob + (size_t)(24u << 20));

  k_cvt_x<<<8192, 256, 0, stream>>>(X, Xb);
  k_cvt_w<<<dim3(50, 16), 256, 0, stream>>>(Wq, Wk, Wv, Ws, Wt);
  k_gemm<<<dim3(25, 64), 256, 0, stream>>>(Xb, Wt, bq, bk, bv, bs, Qw, Kw, Vw, Sw);
  k_scale_q<<<4096, 256, 0, stream>>>(Qw, Sw);
  k_trans_v<<<dim3(32, 64), 256, 0, stream>>>(Vw, Vt);
  k_attn<<<dim3(16, 64), 256, 0, stream>>>(Qw, Kw, Vt, out);
}

// Round 3
// 255.933 us; speedup vs baseline: 1.7459x; 1.7459x over previous
//
#include <hip/hip_runtime.h>
#include <hip/hip_bf16.h>
#include <stdint.h>

typedef short bf16x8 __attribute__((ext_vector_type(8)));
typedef float f32x4 __attribute__((ext_vector_type(4)));
typedef unsigned short u16;
typedef unsigned short u16x4 __attribute__((ext_vector_type(4)));
typedef unsigned short u16x8 __attribute__((ext_vector_type(8)));

#define LOG2E 1.44269504088896f

// sizes
#define Bz 4
#define Sz 2048
#define Hz 1024
#define NHz 16
#define HDz 64

__device__ __forceinline__ u16 f2bf(float f) {
  uint32_t u = __builtin_bit_cast(uint32_t, f);
  u += 0x7fffu + ((u >> 16) & 1u);
  return (u16)(u >> 16);
}
__device__ __forceinline__ float bf2f(u16 h) {
  uint32_t u = ((uint32_t)h) << 16;
  return __builtin_bit_cast(float, u);
}
__device__ __forceinline__ u16 f2bfrn(float f) {
  return __builtin_bit_cast(u16, __float2bfloat16(f));
}

__device__ __forceinline__ void gll16(const void* g, void* l) {
  __builtin_amdgcn_global_load_lds((const __attribute__((address_space(1))) void*)g,
                                   (__attribute__((address_space(3))) void*)l,
                                   16, 0, 0);
}

// ---------------- X (f32) -> bf16 ----------------
__global__ void k_cvt_x(const float* __restrict__ X, u16* __restrict__ Xb) {
  int i = blockIdx.x * 256 + threadIdx.x;
  float4 v = ((const float4*)X)[i];
  u16x4 r;
  r[0] = f2bf(v.x); r[1] = f2bf(v.y); r[2] = f2bf(v.z); r[3] = f2bf(v.w);
  ((u16x4*)Xb)[i] = r;
}

// ------- pack & transpose [Wq|Wk|Wv|Ws] -> Wt[3200][1024] bf16 -------
__global__ void k_cvt_w(const float* __restrict__ Wq, const float* __restrict__ Wk,
                        const float* __restrict__ Wv, const float* __restrict__ Ws,
                        u16* __restrict__ Wt) {
  __shared__ float tile[64][65];
  int n0 = blockIdx.x * 64, k0 = blockIdx.y * 64;
  const float* src; int ld, c0;
  if (n0 < 1024)      { src = Wq; ld = 1024; c0 = n0; }
  else if (n0 < 2048) { src = Wk; ld = 1024; c0 = n0 - 1024; }
  else if (n0 < 3072) { src = Wv; ld = 1024; c0 = n0 - 2048; }
  else                { src = Ws; ld = 128;  c0 = n0 - 3072; }
  int t = threadIdx.x;
  #pragma unroll
  for (int i = 0; i < 16; ++i) {
    int idx = t + i * 256; int r = idx >> 6, c = idx & 63;
    tile[r][c] = src[(size_t)(k0 + r) * ld + c0 + c];
  }
  __syncthreads();
  #pragma unroll
  for (int i = 0; i < 16; ++i) {
    int idx = t + i * 256; int rn = idx >> 6, ck = idx & 63;
    Wt[(size_t)(n0 + rn) * 1024 + k0 + ck] = f2bf(tile[ck][rn]);
  }
}

// ---------------- fused QKV+S GEMM: [8192,1024] x [1024,3200] ----------------
__launch_bounds__(256)
__global__ void k_gemm(const u16* __restrict__ Xb, const u16* __restrict__ Wt,
                       const float* __restrict__ bq, const float* __restrict__ bk,
                       const float* __restrict__ bv, const float* __restrict__ bs,
                       u16* __restrict__ Qw, u16* __restrict__ Kw, u16* __restrict__ Vw,
                       float* __restrict__ Sw) {
  __shared__ u16 As[128 * 32];
  __shared__ u16 Bs[128 * 32];
  int t = threadIdx.x, lane = t & 63;
  int wave = t >> 6, wr = wave >> 1, wc = wave & 1;
  int m0 = blockIdx.y * 128, n0 = blockIdx.x * 128;

  f32x4 acc[4][4];
  #pragma unroll
  for (int i = 0; i < 4; ++i)
    #pragma unroll
    for (int j = 0; j < 4; ++j) { f32x4 z = {0.f,0.f,0.f,0.f}; acc[i][j] = z; }

  int srow = t >> 2;
  int sobyte = (t & 3) << 4;

  for (int kt = 0; kt < 32; ++kt) {
    int kb = kt * 64;
    #pragma unroll
    for (int c = 0; c < 2; ++c) {
      int row = c * 64 + srow;
      int sb = sobyte ^ ((row & 3) << 4);
      gll16((const char*)(Xb + (size_t)(m0 + row) * 1024) + kb + sb,
            (char*)As + row * 64 + sobyte);
    }
    #pragma unroll
    for (int c = 0; c < 2; ++c) {
      int row = c * 64 + srow;
      int sb = sobyte ^ ((row & 3) << 4);
      gll16((const char*)(Wt + (size_t)(n0 + row) * 1024) + kb + sb,
            (char*)Bs + row * 64 + sobyte);
    }
    __syncthreads();
    bf16x8 af[4], bfr[4];
    #pragma unroll
    for (int ai = 0; ai < 4; ++ai) {
      int row = wr * 64 + ai * 16 + (lane & 15);
      int bo = row * 64 + ((((lane >> 4) << 4)) ^ ((row & 3) << 4));
      af[ai] = *(const bf16x8*)((const char*)As + bo);
    }
    #pragma unroll
    for (int bj = 0; bj < 4; ++bj) {
      int row = wc * 64 + bj * 16 + (lane & 15);
      int bo = row * 64 + ((((lane >> 4) << 4)) ^ ((row & 3) << 4));
      bfr[bj] = *(const bf16x8*)((const char*)Bs + bo);
    }
    #pragma unroll
    for (int ai = 0; ai < 4; ++ai)
      #pragma unroll
      for (int bj = 0; bj < 4; ++bj)
        acc[ai][bj] = __builtin_amdgcn_mfma_f32_16x16x32_bf16(af[ai], bfr[bj], acc[ai][bj], 0, 0, 0);
    __syncthreads();
  }

  #pragma unroll
  for (int ai = 0; ai < 4; ++ai) {
    #pragma unroll
    for (int bj = 0; bj < 4; ++bj) {
      #pragma unroll
      for (int r = 0; r < 4; ++r) {
        int m = m0 + wr * 64 + ai * 16 + ((lane >> 4) << 2) + r;
        int j = n0 + wc * 64 + bj * 16 + (lane & 15);
        float v = acc[ai][bj][r];
        int b = m >> 11, si = m & 2047;
        if (j < 3072) {
          float bias = (j < 1024) ? bq[j] : (j < 2048) ? bk[j - 1024] : bv[j - 2048];
          v += bias;
          int jj = j & 1023, h = jj >> 6, d = jj & 63;
          size_t dst = (((size_t)(b * NHz + h) * Sz + si) << 6) + d;
          u16 hv = f2bf(v);
          if (j < 1024) Qw[dst] = hv;
          else if (j < 2048) Kw[dst] = hv;
          else Vw[dst] = hv;
        } else {
          int c = j - 3072;
          v += bs[c];
          float sig = 1.0f / (1.0f + __expf(-v));
          // fold softmax 1/sqrt(64) AND log2(e) (exp->exp2 domain) into Q scale
          Sw[(size_t)m * 128 + c] = (0.9f + 0.2f * sig) * 0.125f * LOG2E;
        }
      }
    }
  }
}

// ---------------- Q *= s (per head,group); s includes 0.125*log2e ----------------
__global__ void k_scale_q(u16* __restrict__ Qw, const float* __restrict__ Sw) {
  int tid = blockIdx.x * 256 + threadIdx.x;
  size_t base = (size_t)tid * 8;
  int bh = (int)(base >> 17);
  int si = (int)((base >> 6) & 2047);
  int d0 = (int)(base & 63);
  int b = bh >> 4, h = bh & 15;
  float s = Sw[((size_t)(b * Sz + si)) * 128 + h * 8 + (d0 >> 3)];
  u16x8 v = *(u16x8*)(Qw + base);
  #pragma unroll
  for (int j = 0; j < 8; ++j) v[j] = f2bf(bf2f(v[j]) * s);
  *(u16x8*)(Qw + base) = v;
}

// ---------------- V [bh][s][d] -> Vt [bh][d][s] ----------------
__global__ void k_trans_v(const u16* __restrict__ Vw, u16* __restrict__ Vt) {
  __shared__ u16 tile[64][65];
  int bh = blockIdx.y, s0 = blockIdx.x * 64;
  int t = threadIdx.x;
  const u16* src = Vw + ((size_t)bh * Sz + s0) * 64;
  #pragma unroll
  for (int i = 0; i < 16; ++i) {
    int idx = t + i * 256; int r = idx >> 6, c = idx & 63;
    tile[r][c] = src[r * 64 + c];
  }
  __syncthreads();
  u16* dst = Vt + (size_t)bh * 64 * Sz;
  #pragma unroll
  for (int i = 0; i < 16; ++i) {
    int idx = t + i * 256; int d = idx >> 6, ss = idx & 63;
    dst[(size_t)d * Sz + s0 + ss] = tile[ss][d];
  }
}

// ---------------- attention: staged dbuf K/V pipeline + in-lane softmax ----------------
// grid (64 bh, 16 q-blocks): all q-tiles of one bh at linear-id stride 64 -> same XCD.
// 4 waves x 32 q-rows; KVBLK=64. Swapped QK^T (mfma(K,Q)) -> P in-lane; exp2, no max;
// P relayout via wave-private swizzled LDS; l reduced once at the end.
__launch_bounds__(256)
__global__ void k_attn(const u16* __restrict__ Qw, const u16* __restrict__ Kw,
                       const u16* __restrict__ Vt, float* __restrict__ out) {
  __shared__ u16 Kl[2][64 * 64];   // [kv][d] bytes, rows 128B, XOR-swizzled
  __shared__ u16 Vl[2][64 * 64];   // [d][kv] bytes, rows 128B, XOR-swizzled
  __shared__ u16 Pl[4][32 * 64];   // per-wave P [q][kv], XOR-swizzled

  int t = threadIdx.x, lane = t & 63, wave = t >> 6;
  int l15 = lane & 15, g = lane >> 4;
  int bh = blockIdx.x, b = bh >> 4, h = bh & 15;
  int q0 = blockIdx.y * 128 + wave * 32;

  const u16* Qb = Qw + (size_t)bh * Sz * 64;
  const char* Kg = (const char*)(Kw + (size_t)bh * Sz * 64);
  const char* Vg = (const char*)(Vt + (size_t)bh * 64 * Sz);
  u16* Pw = Pl[wave];
  int swp = (l15 & 7) << 4;        // P swizzle (row & 7 == l15 & 7)

  // staging coords: 256 threads stage 64 rows x 128B for K and V
  int srow = t >> 3;               // 0..31
  int sobyte = (t & 7) << 4;       // 0..112

  // Q fragments: [qi][ks], row q0+16qi+l15, d = 32ks+8g..+7 (pre-scaled by k_scale_q)
  bf16x8 qf[2][2];
  #pragma unroll
  for (int qi = 0; qi < 2; ++qi)
    #pragma unroll
    for (int ks = 0; ks < 2; ++ks)
      qf[qi][ks] = *(const bf16x8*)(Qb + (size_t)(q0 + 16 * qi + l15) * 64 + 32 * ks + 8 * g);

  f32x4 o[2][4];
  #pragma unroll
  for (int qi = 0; qi < 2; ++qi)
    #pragma unroll
    for (int nt = 0; nt < 4; ++nt) { f32x4 z = {0.f,0.f,0.f,0.f}; o[qi][nt] = z; }
  float lsum[2] = {0.f, 0.f};

  // prologue: stage tile 0 into buf 0
  #pragma unroll
  for (int c = 0; c < 2; ++c) {
    int row = c * 32 + srow;
    int sw2 = (row & 7) << 4;
    gll16(Kg + (size_t)row * 128 + (sobyte ^ sw2), (char*)Kl[0] + row * 128 + sobyte);
    gll16(Vg + (size_t)row * (Sz * 2) + (sobyte ^ sw2), (char*)Vl[0] + row * 128 + sobyte);
  }
  __syncthreads();

  int cur = 0;
  for (int kv0 = 0; kv0 < Sz; kv0 += 64) {
    // issue next tile's async stage (overlaps with compute below)
    if (kv0 + 64 < Sz) {
      int nxt = cur ^ 1, kvn = kv0 + 64;
      #pragma unroll
      for (int c = 0; c < 2; ++c) {
        int row = c * 32 + srow;
        int sw2 = (row & 7) << 4;
        gll16(Kg + (size_t)(kvn + row) * 128 + (sobyte ^ sw2),
              (char*)Kl[nxt] + row * 128 + sobyte);
        gll16(Vg + (size_t)row * (Sz * 2) + (size_t)kvn * 2 + (sobyte ^ sw2),
              (char*)Vl[nxt] + row * 128 + sobyte);
      }
    }
    const char* Kb = (const char*)Kl[cur];
    const char* Vb = (const char*)Vl[cur];

    // ---- QK^T (swapped): sc[qi][nt] holds S[kv=16nt+4g+r][q=16qi+l15] ----
    f32x4 sc[2][4];
    #pragma unroll
    for (int nt = 0; nt < 4; ++nt) {
      int row = 16 * nt + l15;
      int sw2 = (row & 7) << 4;
      bf16x8 kf0 = *(const bf16x8*)(Kb + row * 128 + ((16 * g) ^ sw2));
      bf16x8 kf1 = *(const bf16x8*)(Kb + row * 128 + ((64 + 16 * g) ^ sw2));
      #pragma unroll
      for (int qi = 0; qi < 2; ++qi) {
        f32x4 a = {0.f,0.f,0.f,0.f};
        a = __builtin_amdgcn_mfma_f32_16x16x32_bf16(kf0, qf[qi][0], a, 0, 0, 0);
        a = __builtin_amdgcn_mfma_f32_16x16x32_bf16(kf1, qf[qi][1], a, 0, 0, 0);
        sc[qi][nt] = a;
      }
    }
    // ---- p = exp2(S'), accumulate l, pack P -> wave-private LDS ----
    #pragma unroll
    for (int qi = 0; qi < 2; ++qi) {
      int rbase = (16 * qi + l15) * 128;
      #pragma unroll
      for (int nt = 0; nt < 4; ++nt) {
        float p0 = __builtin_amdgcn_exp2f(sc[qi][nt][0]);
        float p1 = __builtin_amdgcn_exp2f(sc[qi][nt][1]);
        float p2 = __builtin_amdgcn_exp2f(sc[qi][nt][2]);
        float p3 = __builtin_amdgcn_exp2f(sc[qi][nt][3]);
        lsum[qi] += (p0 + p1) + (p2 + p3);
        u16x4 pk;
        pk[0] = f2bfrn(p0); pk[1] = f2bfrn(p1);
        pk[2] = f2bfrn(p2); pk[3] = f2bfrn(p3);
        *(u16x4*)((char*)Pw + rbase + ((32 * nt + 8 * g) ^ swp)) = pk;
      }
    }
    // ---- PV: o[qi][nt] += P(32x64) @ V(64x64) ----
    #pragma unroll
    for (int ks = 0; ks < 2; ++ks) {
      bf16x8 pa[2];
      #pragma unroll
      for (int qi = 0; qi < 2; ++qi)
        pa[qi] = *(const bf16x8*)((char*)Pw + (16 * qi + l15) * 128 + ((64 * ks + 16 * g) ^ swp));
      #pragma unroll
      for (int nt = 0; nt < 4; ++nt) {
        int row = 16 * nt + l15;
        int sw2 = (row & 7) << 4;
        bf16x8 vf = *(const bf16x8*)(Vb + row * 128 + ((64 * ks + 16 * g) ^ sw2));
        o[0][nt] = __builtin_amdgcn_mfma_f32_16x16x32_bf16(pa[0], vf, o[0][nt], 0, 0, 0);
        o[1][nt] = __builtin_amdgcn_mfma_f32_16x16x32_bf16(pa[1], vf, o[1][nt], 0, 0, 0);
      }
    }
    __syncthreads();   // staged next tile complete (vmcnt0) + all waves done with cur
    cur ^= 1;
  }

  // ---- final l reduction across the 4 lane-groups, then write ----
  #pragma unroll
  for (int qi = 0; qi < 2; ++qi) {
    float l = lsum[qi];
    l += __shfl_xor(l, 16);
    l += __shfl_xor(l, 32);
    lsum[qi] = 1.0f / l;
  }
  #pragma unroll
  for (int qi = 0; qi < 2; ++qi) {
    float li[4];
    #pragma unroll
    for (int r = 0; r < 4; ++r) li[r] = __shfl(lsum[qi], 4 * g + r);
    #pragma unroll
    for (int nt = 0; nt < 4; ++nt)
      #pragma unroll
      for (int r = 0; r < 4; ++r)
        out[((size_t)(b * Sz + q0 + 16 * qi + 4 * g + r)) * (NHz * HDz) +
            h * 64 + 16 * nt + l15] = o[qi][nt][r] * li[r];
  }
}

extern "C" void kernel_launch(void* const* d_in, const int* in_sizes, int n_in,
                              void* d_out, int out_size, void* d_ws, size_t ws_size,
                              hipStream_t stream) {
  const float* X  = (const float*)d_in[0];
  const float* Wq = (const float*)d_in[1];
  const float* bq = (const float*)d_in[2];
  const float* Wk = (const float*)d_in[3];
  const float* bk = (const float*)d_in[4];
  const float* Wv = (const float*)d_in[5];
  const float* bv = (const float*)d_in[6];
  const float* Ws = (const float*)d_in[7];
  const float* bs = (const float*)d_in[8];
  float* out = (float*)d_out;

  // ws: Qw | Kw | Vw | Vt  (16 MB each)
  char* ws = (char*)d_ws;
  u16* Qw = (u16*)(ws);
  u16* Kw = (u16*)(ws + (size_t)(16u << 20));
  u16* Vw = (u16*)(ws + (size_t)(32u << 20));
  u16* Vt = (u16*)(ws + (size_t)(48u << 20));

  // d_out doubles as scratch: Xb (16MB) | Wt (6.55MB) | Sw (4MB); all consumed
  // before k_attn overwrites the output.
  char* ob = (char*)d_out;
  u16* Xb   = (u16*)ob;
  u16* Wt   = (u16*)(ob + (size_t)(16u << 20));
  float* Sw = (float*)(ob + (size_t)(24u << 20));

  k_cvt_x<<<8192, 256, 0, stream>>>(X, Xb);
  k_cvt_w<<<dim3(50, 16), 256, 0, stream>>>(Wq, Wk, Wv, Ws, Wt);
  k_gemm<<<dim3(25, 64), 256, 0, stream>>>(Xb, Wt, bq, bk, bv, bs, Qw, Kw, Vw, Sw);
  k_scale_q<<<4096, 256, 0, stream>>>(Qw, Sw);
  k_trans_v<<<dim3(32, 64), 256, 0, stream>>>(Vw, Vt);
  k_attn<<<dim3(64, 16), 256, 0, stream>>>(Qw, Kw, Vt, out);
}

// Round 4
// 241.070 us; speedup vs baseline: 1.8535x; 1.0617x over previous
//
#include <hip/hip_runtime.h>
#include <hip/hip_bf16.h>
#include <stdint.h>

typedef short bf16x8 __attribute__((ext_vector_type(8)));
typedef float f32x4 __attribute__((ext_vector_type(4)));
typedef unsigned short u16;
typedef unsigned short u16x4 __attribute__((ext_vector_type(4)));
typedef unsigned short u16x8 __attribute__((ext_vector_type(8)));

#define LOG2E 1.44269504088896f

// sizes
#define Bz 4
#define Sz 2048
#define Hz 1024
#define NHz 16
#define HDz 64

__device__ __forceinline__ u16 f2bf(float f) {
  uint32_t u = __builtin_bit_cast(uint32_t, f);
  u += 0x7fffu + ((u >> 16) & 1u);
  return (u16)(u >> 16);
}
__device__ __forceinline__ float bf2f(u16 h) {
  uint32_t u = ((uint32_t)h) << 16;
  return __builtin_bit_cast(float, u);
}
__device__ __forceinline__ u16 f2bfrn(float f) {
  return __builtin_bit_cast(u16, __float2bfloat16(f));
}

__device__ __forceinline__ void gll16(const void* g, void* l) {
  __builtin_amdgcn_global_load_lds((const __attribute__((address_space(1))) void*)g,
                                   (__attribute__((address_space(3))) void*)l,
                                   16, 0, 0);
}

// ---------------- X (f32) -> bf16 ----------------
__global__ void k_cvt_x(const float* __restrict__ X, u16* __restrict__ Xb) {
  int i = blockIdx.x * 256 + threadIdx.x;
  float4 v = ((const float4*)X)[i];
  u16x4 r;
  r[0] = f2bf(v.x); r[1] = f2bf(v.y); r[2] = f2bf(v.z); r[3] = f2bf(v.w);
  ((u16x4*)Xb)[i] = r;
}

// ------- pack & transpose [Wq|Wk|Wv|Ws] -> Wt[3200][1024] bf16 -------
__global__ void k_cvt_w(const float* __restrict__ Wq, const float* __restrict__ Wk,
                        const float* __restrict__ Wv, const float* __restrict__ Ws,
                        u16* __restrict__ Wt) {
  __shared__ float tile[64][65];
  int n0 = blockIdx.x * 64, k0 = blockIdx.y * 64;
  const float* src; int ld, c0;
  if (n0 < 1024)      { src = Wq; ld = 1024; c0 = n0; }
  else if (n0 < 2048) { src = Wk; ld = 1024; c0 = n0 - 1024; }
  else if (n0 < 3072) { src = Wv; ld = 1024; c0 = n0 - 2048; }
  else                { src = Ws; ld = 128;  c0 = n0 - 3072; }
  int t = threadIdx.x;
  #pragma unroll
  for (int i = 0; i < 16; ++i) {
    int idx = t + i * 256; int r = idx >> 6, c = idx & 63;
    tile[r][c] = src[(size_t)(k0 + r) * ld + c0 + c];
  }
  __syncthreads();
  #pragma unroll
  for (int i = 0; i < 16; ++i) {
    int idx = t + i * 256; int rn = idx >> 6, ck = idx & 63;
    Wt[(size_t)(n0 + rn) * 1024 + k0 + ck] = f2bf(tile[ck][rn]);
  }
}

// ---------------- fused QKV+S GEMM: [8192,1024] x [1024,3200] ----------------
// 128x128 tile, BK=64, double-buffered LDS, prefetch-before-compute (T3-min),
// one barrier per K-step, row&7 XOR swizzle (conflict-free 128B rows).
__launch_bounds__(256)
__global__ void k_gemm(const u16* __restrict__ Xb, const u16* __restrict__ Wt,
                       const float* __restrict__ bq, const float* __restrict__ bk,
                       const float* __restrict__ bv, const float* __restrict__ bs,
                       u16* __restrict__ Qw, u16* __restrict__ Kw, u16* __restrict__ Vw,
                       float* __restrict__ Sw) {
  __shared__ u16 As[2][128 * 64];   // 16KB each
  __shared__ u16 Bs[2][128 * 64];
  int t = threadIdx.x, lane = t & 63;
  int l15 = lane & 15, g = lane >> 4;
  int wave = t >> 6, wr = wave >> 1, wc = wave & 1;
  int m0 = blockIdx.y * 128, n0 = blockIdx.x * 128;

  f32x4 acc[4][4];
  #pragma unroll
  for (int i = 0; i < 4; ++i)
    #pragma unroll
    for (int j = 0; j < 4; ++j) { f32x4 z = {0.f,0.f,0.f,0.f}; acc[i][j] = z; }

  int srow = t >> 3;               // 0..31
  int sob  = (t & 7) << 4;         // 0..112

  const char* Ag = (const char*)Xb;
  const char* Bg = (const char*)Wt;

  // prologue: stage K-step 0 into buf 0
  #pragma unroll
  for (int c = 0; c < 4; ++c) {
    int row = c * 32 + srow;
    int sb = sob ^ ((row & 7) << 4);
    gll16(Ag + (size_t)(m0 + row) * 2048 + sb, (char*)As[0] + row * 128 + sob);
    gll16(Bg + (size_t)(n0 + row) * 2048 + sb, (char*)Bs[0] + row * 128 + sob);
  }
  __syncthreads();

  int cur = 0;
  for (int kt = 0; kt < 16; ++kt) {
    // prefetch next K-tile into the other buffer (overlaps compute below)
    if (kt + 1 < 16) {
      int nxt = cur ^ 1;
      size_t kb = (size_t)(kt + 1) * 128;
      #pragma unroll
      for (int c = 0; c < 4; ++c) {
        int row = c * 32 + srow;
        int sb = sob ^ ((row & 7) << 4);
        gll16(Ag + (size_t)(m0 + row) * 2048 + kb + sb, (char*)As[nxt] + row * 128 + sob);
        gll16(Bg + (size_t)(n0 + row) * 2048 + kb + sb, (char*)Bs[nxt] + row * 128 + sob);
      }
    }
    const char* Ab = (const char*)As[cur];
    const char* Bb = (const char*)Bs[cur];
    #pragma unroll
    for (int ksub = 0; ksub < 2; ++ksub) {
      bf16x8 af[4], bfr[4];
      #pragma unroll
      for (int ai = 0; ai < 4; ++ai) {
        int row = wr * 64 + ai * 16 + l15;
        af[ai] = *(const bf16x8*)(Ab + row * 128 + ((ksub * 64 + 16 * g) ^ ((row & 7) << 4)));
      }
      #pragma unroll
      for (int bj = 0; bj < 4; ++bj) {
        int row = wc * 64 + bj * 16 + l15;
        bfr[bj] = *(const bf16x8*)(Bb + row * 128 + ((ksub * 64 + 16 * g) ^ ((row & 7) << 4)));
      }
      #pragma unroll
      for (int ai = 0; ai < 4; ++ai)
        #pragma unroll
        for (int bj = 0; bj < 4; ++bj)
          acc[ai][bj] = __builtin_amdgcn_mfma_f32_16x16x32_bf16(af[ai], bfr[bj], acc[ai][bj], 0, 0, 0);
    }
    __syncthreads();   // drains prefetch (vmcnt0) + all waves done reading cur
    cur ^= 1;
  }

  #pragma unroll
  for (int ai = 0; ai < 4; ++ai) {
    #pragma unroll
    for (int bj = 0; bj < 4; ++bj) {
      #pragma unroll
      for (int r = 0; r < 4; ++r) {
        int m = m0 + wr * 64 + ai * 16 + ((lane >> 4) << 2) + r;
        int j = n0 + wc * 64 + bj * 16 + l15;
        float v = acc[ai][bj][r];
        int b = m >> 11, si = m & 2047;
        if (j < 3072) {
          float bias = (j < 1024) ? bq[j] : (j < 2048) ? bk[j - 1024] : bv[j - 2048];
          v += bias;
          int jj = j & 1023, h = jj >> 6, d = jj & 63;
          size_t dst = (((size_t)(b * NHz + h) * Sz + si) << 6) + d;
          u16 hv = f2bf(v);
          if (j < 1024) Qw[dst] = hv;
          else if (j < 2048) Kw[dst] = hv;
          else Vw[dst] = hv;
        } else {
          int c = j - 3072;
          v += bs[c];
          float sig = 1.0f / (1.0f + __expf(-v));
          // fold softmax 1/sqrt(64) AND log2(e) (exp->exp2 domain) into Q scale
          Sw[(size_t)m * 128 + c] = (0.9f + 0.2f * sig) * 0.125f * LOG2E;
        }
      }
    }
  }
}

// ---------------- fallback: Q *= s (only if ws can't hold Sw) ----------------
__global__ void k_scale_q(u16* __restrict__ Qw, const float* __restrict__ Sw) {
  int tid = blockIdx.x * 256 + threadIdx.x;
  size_t base = (size_t)tid * 8;
  int bh = (int)(base >> 17);
  int si = (int)((base >> 6) & 2047);
  int d0 = (int)(base & 63);
  int b = bh >> 4, h = bh & 15;
  float s = Sw[((size_t)(b * Sz + si)) * 128 + h * 8 + (d0 >> 3)];
  u16x8 v = *(u16x8*)(Qw + base);
  #pragma unroll
  for (int j = 0; j < 8; ++j) v[j] = f2bf(bf2f(v[j]) * s);
  *(u16x8*)(Qw + base) = v;
}

// ---------------- V [bh][s][d] -> Vt [bh][d][s] ----------------
__global__ void k_trans_v(const u16* __restrict__ Vw, u16* __restrict__ Vt) {
  __shared__ u16 tile[64][65];
  int bh = blockIdx.y, s0 = blockIdx.x * 64;
  int t = threadIdx.x;
  const u16* src = Vw + ((size_t)bh * Sz + s0) * 64;
  #pragma unroll
  for (int i = 0; i < 16; ++i) {
    int idx = t + i * 256; int r = idx >> 6, c = idx & 63;
    tile[r][c] = src[r * 64 + c];
  }
  __syncthreads();
  u16* dst = Vt + (size_t)bh * 64 * Sz;
  #pragma unroll
  for (int i = 0; i < 16; ++i) {
    int idx = t + i * 256; int d = idx >> 6, ss = idx & 63;
    dst[(size_t)d * Sz + s0 + ss] = tile[ss][d];
  }
}

// ---------------- attention: staged dbuf K/V pipeline + in-lane softmax ----------------
// grid (64 bh, 16 q-blocks). 4 waves x 32 q-rows; KVBLK=64. Swapped QK^T; exp2 no-max;
// P via wave-private swizzled LDS; Q scaled in f32 at load (Swp) or pre-scaled (nullptr).
__launch_bounds__(256)
__global__ void k_attn(const u16* __restrict__ Qw, const u16* __restrict__ Kw,
                       const u16* __restrict__ Vt, const float* __restrict__ Swp,
                       float* __restrict__ out) {
  __shared__ u16 Kl[2][64 * 64];
  __shared__ u16 Vl[2][64 * 64];
  __shared__ u16 Pl[4][32 * 64];

  int t = threadIdx.x, lane = t & 63, wave = t >> 6;
  int l15 = lane & 15, g = lane >> 4;
  int bh = blockIdx.x, b = bh >> 4, h = bh & 15;
  int q0 = blockIdx.y * 128 + wave * 32;

  const u16* Qb = Qw + (size_t)bh * Sz * 64;
  const char* Kg = (const char*)(Kw + (size_t)bh * Sz * 64);
  const char* Vg = (const char*)(Vt + (size_t)bh * 64 * Sz);
  u16* Pw = Pl[wave];
  int swp = (l15 & 7) << 4;

  int srow = t >> 3;
  int sobyte = (t & 7) << 4;

  bf16x8 qf[2][2];
  #pragma unroll
  for (int qi = 0; qi < 2; ++qi)
    #pragma unroll
    for (int ks = 0; ks < 2; ++ks)
      qf[qi][ks] = *(const bf16x8*)(Qb + (size_t)(q0 + 16 * qi + l15) * 64 + 32 * ks + 8 * g);
  if (Swp) {
    #pragma unroll
    for (int qi = 0; qi < 2; ++qi) {
      size_t m = (size_t)(b * Sz + q0 + 16 * qi + l15);
      #pragma unroll
      for (int ks = 0; ks < 2; ++ks) {
        float s = Swp[m * 128 + h * 8 + 4 * ks + g];
        bf16x8 q = qf[qi][ks];
        #pragma unroll
        for (int j = 0; j < 8; ++j) q[j] = (short)f2bf(bf2f((u16)q[j]) * s);
        qf[qi][ks] = q;
      }
    }
  }

  f32x4 o[2][4];
  #pragma unroll
  for (int qi = 0; qi < 2; ++qi)
    #pragma unroll
    for (int nt = 0; nt < 4; ++nt) { f32x4 z = {0.f,0.f,0.f,0.f}; o[qi][nt] = z; }
  float lsum[2] = {0.f, 0.f};

  #pragma unroll
  for (int c = 0; c < 2; ++c) {
    int row = c * 32 + srow;
    int sw2 = (row & 7) << 4;
    gll16(Kg + (size_t)row * 128 + (sobyte ^ sw2), (char*)Kl[0] + row * 128 + sobyte);
    gll16(Vg + (size_t)row * (Sz * 2) + (sobyte ^ sw2), (char*)Vl[0] + row * 128 + sobyte);
  }
  __syncthreads();

  int cur = 0;
  for (int kv0 = 0; kv0 < Sz; kv0 += 64) {
    if (kv0 + 64 < Sz) {
      int nxt = cur ^ 1, kvn = kv0 + 64;
      #pragma unroll
      for (int c = 0; c < 2; ++c) {
        int row = c * 32 + srow;
        int sw2 = (row & 7) << 4;
        gll16(Kg + (size_t)(kvn + row) * 128 + (sobyte ^ sw2),
              (char*)Kl[nxt] + row * 128 + sobyte);
        gll16(Vg + (size_t)row * (Sz * 2) + (size_t)kvn * 2 + (sobyte ^ sw2),
              (char*)Vl[nxt] + row * 128 + sobyte);
      }
    }
    const char* Kb = (const char*)Kl[cur];
    const char* Vb = (const char*)Vl[cur];

    f32x4 sc[2][4];
    __builtin_amdgcn_s_setprio(1);
    #pragma unroll
    for (int nt = 0; nt < 4; ++nt) {
      int row = 16 * nt + l15;
      int sw2 = (row & 7) << 4;
      bf16x8 kf0 = *(const bf16x8*)(Kb + row * 128 + ((16 * g) ^ sw2));
      bf16x8 kf1 = *(const bf16x8*)(Kb + row * 128 + ((64 + 16 * g) ^ sw2));
      #pragma unroll
      for (int qi = 0; qi < 2; ++qi) {
        f32x4 a = {0.f,0.f,0.f,0.f};
        a = __builtin_amdgcn_mfma_f32_16x16x32_bf16(kf0, qf[qi][0], a, 0, 0, 0);
        a = __builtin_amdgcn_mfma_f32_16x16x32_bf16(kf1, qf[qi][1], a, 0, 0, 0);
        sc[qi][nt] = a;
      }
    }
    __builtin_amdgcn_s_setprio(0);
    #pragma unroll
    for (int qi = 0; qi < 2; ++qi) {
      int rbase = (16 * qi + l15) * 128;
      #pragma unroll
      for (int nt = 0; nt < 4; ++nt) {
        float p0 = __builtin_amdgcn_exp2f(sc[qi][nt][0]);
        float p1 = __builtin_amdgcn_exp2f(sc[qi][nt][1]);
        float p2 = __builtin_amdgcn_exp2f(sc[qi][nt][2]);
        float p3 = __builtin_amdgcn_exp2f(sc[qi][nt][3]);
        lsum[qi] += (p0 + p1) + (p2 + p3);
        u16x4 pk;
        pk[0] = f2bfrn(p0); pk[1] = f2bfrn(p1);
        pk[2] = f2bfrn(p2); pk[3] = f2bfrn(p3);
        *(u16x4*)((char*)Pw + rbase + ((32 * nt + 8 * g) ^ swp)) = pk;
      }
    }
    __builtin_amdgcn_s_setprio(1);
    #pragma unroll
    for (int ks = 0; ks < 2; ++ks) {
      bf16x8 pa[2];
      #pragma unroll
      for (int qi = 0; qi < 2; ++qi)
        pa[qi] = *(const bf16x8*)((char*)Pw + (16 * qi + l15) * 128 + ((64 * ks + 16 * g) ^ swp));
      #pragma unroll
      for (int nt = 0; nt < 4; ++nt) {
        int row = 16 * nt + l15;
        int sw2 = (row & 7) << 4;
        bf16x8 vf = *(const bf16x8*)(Vb + row * 128 + ((64 * ks + 16 * g) ^ sw2));
        o[0][nt] = __builtin_amdgcn_mfma_f32_16x16x32_bf16(pa[0], vf, o[0][nt], 0, 0, 0);
        o[1][nt] = __builtin_amdgcn_mfma_f32_16x16x32_bf16(pa[1], vf, o[1][nt], 0, 0, 0);
      }
    }
    __builtin_amdgcn_s_setprio(0);
    __syncthreads();
    cur ^= 1;
  }

  #pragma unroll
  for (int qi = 0; qi < 2; ++qi) {
    float l = lsum[qi];
    l += __shfl_xor(l, 16);
    l += __shfl_xor(l, 32);
    lsum[qi] = 1.0f / l;
  }
  #pragma unroll
  for (int qi = 0; qi < 2; ++qi) {
    float li[4];
    #pragma unroll
    for (int r = 0; r < 4; ++r) li[r] = __shfl(lsum[qi], 4 * g + r);
    #pragma unroll
    for (int nt = 0; nt < 4; ++nt)
      #pragma unroll
      for (int r = 0; r < 4; ++r)
        out[((size_t)(b * Sz + q0 + 16 * qi + 4 * g + r)) * (NHz * HDz) +
            h * 64 + 16 * nt + l15] = o[qi][nt][r] * li[r];
  }
}

extern "C" void kernel_launch(void* const* d_in, const int* in_sizes, int n_in,
                              void* d_out, int out_size, void* d_ws, size_t ws_size,
                              hipStream_t stream) {
  const float* X  = (const float*)d_in[0];
  const float* Wq = (const float*)d_in[1];
  const float* bq = (const float*)d_in[2];
  const float* Wk = (const float*)d_in[3];
  const float* bk = (const float*)d_in[4];
  const float* Wv = (const float*)d_in[5];
  const float* bv = (const float*)d_in[6];
  const float* Ws = (const float*)d_in[7];
  const float* bs = (const float*)d_in[8];
  float* out = (float*)d_out;

  // ws: Qw | Kw | Vw | Vt (16 MB each) [+ Sw 4MB if room]
  char* ws = (char*)d_ws;
  u16* Qw = (u16*)(ws);
  u16* Kw = (u16*)(ws + (size_t)(16u << 20));
  u16* Vw = (u16*)(ws + (size_t)(32u << 20));
  u16* Vt = (u16*)(ws + (size_t)(48u << 20));

  // d_out scratch: Xb (16MB) | Wt (6.55MB) — consumed by k_gemm before attn writes.
  char* ob = (char*)d_out;
  u16* Xb   = (u16*)ob;
  u16* Wt   = (u16*)(ob + (size_t)(16u << 20));

  bool fused = ws_size >= ((size_t)(64u << 20) + (size_t)(4u << 20));
  float* Sw = fused ? (float*)(ws + (size_t)(64u << 20))
                    : (float*)(ob + (size_t)(24u << 20));  // fallback: consumed pre-attn

  k_cvt_x<<<8192, 256, 0, stream>>>(X, Xb);
  k_cvt_w<<<dim3(50, 16), 256, 0, stream>>>(Wq, Wk, Wv, Ws, Wt);
  k_gemm<<<dim3(25, 64), 256, 0, stream>>>(Xb, Wt, bq, bk, bv, bs, Qw, Kw, Vw, Sw);
  if (!fused) k_scale_q<<<4096, 256, 0, stream>>>(Qw, Sw);
  k_trans_v<<<dim3(32, 64), 256, 0, stream>>>(Vw, Vt);
  k_attn<<<dim3(64, 16), 256, 0, stream>>>(Qw, Kw, Vt, fused ? Sw : nullptr, out);
}

// Round 5
// 213.994 us; speedup vs baseline: 2.0880x; 1.1265x over previous
//
#include <hip/hip_runtime.h>
#include <hip/hip_bf16.h>
#include <stdint.h>

typedef short bf16x8 __attribute__((ext_vector_type(8)));
typedef float f32x4 __attribute__((ext_vector_type(4)));
typedef unsigned short u16;
typedef unsigned short u16x4 __attribute__((ext_vector_type(4)));
typedef unsigned short u16x8 __attribute__((ext_vector_type(8)));

#define LOG2E 1.44269504088896f

// sizes
#define Bz 4
#define Sz 2048
#define Hz 1024
#define NHz 16
#define HDz 64

__device__ __forceinline__ u16 f2bf(float f) {
  uint32_t u = __builtin_bit_cast(uint32_t, f);
  u += 0x7fffu + ((u >> 16) & 1u);
  return (u16)(u >> 16);
}
__device__ __forceinline__ float bf2f(u16 h) {
  uint32_t u = ((uint32_t)h) << 16;
  return __builtin_bit_cast(float, u);
}
__device__ __forceinline__ u16 f2bfrn(float f) {
  return __builtin_bit_cast(u16, __float2bfloat16(f));
}

__device__ __forceinline__ void gll16(const void* g, void* l) {
  __builtin_amdgcn_global_load_lds((const __attribute__((address_space(1))) void*)g,
                                   (__attribute__((address_space(3))) void*)l,
                                   16, 0, 0);
}

// ---------------- X (f32) -> bf16 ----------------
__global__ void k_cvt_x(const float* __restrict__ X, u16* __restrict__ Xb) {
  int i = blockIdx.x * 256 + threadIdx.x;
  float4 v = ((const float4*)X)[i];
  u16x4 r;
  r[0] = f2bf(v.x); r[1] = f2bf(v.y); r[2] = f2bf(v.z); r[3] = f2bf(v.w);
  ((u16x4*)Xb)[i] = r;
}

// ------- pack & transpose [Wq|Wk|Wv|Ws] -> Wt[3200][1024] bf16 -------
__global__ void k_cvt_w(const float* __restrict__ Wq, const float* __restrict__ Wk,
                        const float* __restrict__ Wv, const float* __restrict__ Ws,
                        u16* __restrict__ Wt) {
  __shared__ float tile[64][65];
  int n0 = blockIdx.x * 64, k0 = blockIdx.y * 64;
  const float* src; int ld, c0;
  if (n0 < 1024)      { src = Wq; ld = 1024; c0 = n0; }
  else if (n0 < 2048) { src = Wk; ld = 1024; c0 = n0 - 1024; }
  else if (n0 < 3072) { src = Wv; ld = 1024; c0 = n0 - 2048; }
  else                { src = Ws; ld = 128;  c0 = n0 - 3072; }
  int t = threadIdx.x;
  #pragma unroll
  for (int i = 0; i < 16; ++i) {
    int idx = t + i * 256; int r = idx >> 6, c = idx & 63;
    tile[r][c] = src[(size_t)(k0 + r) * ld + c0 + c];
  }
  __syncthreads();
  #pragma unroll
  for (int i = 0; i < 16; ++i) {
    int idx = t + i * 256; int rn = idx >> 6, ck = idx & 63;
    Wt[(size_t)(n0 + rn) * 1024 + k0 + ck] = f2bf(tile[ck][rn]);
  }
}

// ---------------- fused QKV+S GEMM: [8192,1024] x [1024,3200] ----------------
// 128x128 tile, BK=64, dbuf LDS, prefetch-before-compute, 1 barrier/K-step,
// row&7 XOR swizzle (conflict-free). 512 threads (8 waves, 2M x 4N) -> 2 blk/CU
// = 16 waves/CU. Bijective XCD-aware mapping: each XCD owns an 8-m-tile row
// (A panel 2MB L2-resident); 8 consecutive blocks share one B panel.
__launch_bounds__(512, 4)
__global__ void k_gemm(const u16* __restrict__ Xb, const u16* __restrict__ Wt,
                       const float* __restrict__ bq, const float* __restrict__ bk,
                       const float* __restrict__ bv, const float* __restrict__ bs,
                       u16* __restrict__ Qw, u16* __restrict__ Kw, u16* __restrict__ Vw,
                       float* __restrict__ Sw) {
  __shared__ u16 As[2][128 * 64];   // 16KB each
  __shared__ u16 Bs[2][128 * 64];
  int t = threadIdx.x, lane = t & 63;
  int l15 = lane & 15, g = lane >> 4;
  int wave = t >> 6, wr = wave >> 2, wc = wave & 3;

  // XCD-aware bijective mapping (1600 = 8 XCDs x 200)
  int p = blockIdx.x;
  int xcd = p & 7;
  int idx = p >> 3;            // 0..199
  int n_t = idx >> 3;          // 0..24
  int m_t = xcd * 8 + (idx & 7);
  int m0 = m_t * 128, n0 = n_t * 128;

  f32x4 acc[4][2];
  #pragma unroll
  for (int i = 0; i < 4; ++i)
    #pragma unroll
    for (int j = 0; j < 2; ++j) { f32x4 z = {0.f,0.f,0.f,0.f}; acc[i][j] = z; }

  int srow = t >> 3;               // 0..63
  int sob  = (t & 7) << 4;         // 0..112

  const char* Ag = (const char*)Xb;
  const char* Bg = (const char*)Wt;

  // prologue: stage K-step 0 into buf 0
  #pragma unroll
  for (int c = 0; c < 2; ++c) {
    int row = c * 64 + srow;
    int sb = sob ^ ((row & 7) << 4);
    gll16(Ag + (size_t)(m0 + row) * 2048 + sb, (char*)As[0] + row * 128 + sob);
    gll16(Bg + (size_t)(n0 + row) * 2048 + sb, (char*)Bs[0] + row * 128 + sob);
  }
  __syncthreads();

  int cur = 0;
  for (int kt = 0; kt < 16; ++kt) {
    if (kt + 1 < 16) {
      int nxt = cur ^ 1;
      size_t kb = (size_t)(kt + 1) * 128;
      #pragma unroll
      for (int c = 0; c < 2; ++c) {
        int row = c * 64 + srow;
        int sb = sob ^ ((row & 7) << 4);
        gll16(Ag + (size_t)(m0 + row) * 2048 + kb + sb, (char*)As[nxt] + row * 128 + sob);
        gll16(Bg + (size_t)(n0 + row) * 2048 + kb + sb, (char*)Bs[nxt] + row * 128 + sob);
      }
    }
    const char* Ab = (const char*)As[cur];
    const char* Bb = (const char*)Bs[cur];
    #pragma unroll
    for (int ksub = 0; ksub < 2; ++ksub) {
      bf16x8 af[4], bfr[2];
      #pragma unroll
      for (int ai = 0; ai < 4; ++ai) {
        int row = wr * 64 + ai * 16 + l15;
        af[ai] = *(const bf16x8*)(Ab + row * 128 + ((ksub * 64 + 16 * g) ^ ((row & 7) << 4)));
      }
      #pragma unroll
      for (int bj = 0; bj < 2; ++bj) {
        int row = wc * 32 + bj * 16 + l15;
        bfr[bj] = *(const bf16x8*)(Bb + row * 128 + ((ksub * 64 + 16 * g) ^ ((row & 7) << 4)));
      }
      #pragma unroll
      for (int ai = 0; ai < 4; ++ai)
        #pragma unroll
        for (int bj = 0; bj < 2; ++bj)
          acc[ai][bj] = __builtin_amdgcn_mfma_f32_16x16x32_bf16(af[ai], bfr[bj], acc[ai][bj], 0, 0, 0);
    }
    __syncthreads();   // drains prefetch + all waves done reading cur
    cur ^= 1;
  }

  #pragma unroll
  for (int ai = 0; ai < 4; ++ai) {
    #pragma unroll
    for (int bj = 0; bj < 2; ++bj) {
      #pragma unroll
      for (int r = 0; r < 4; ++r) {
        int m = m0 + wr * 64 + ai * 16 + ((lane >> 4) << 2) + r;
        int j = n0 + wc * 32 + bj * 16 + l15;
        float v = acc[ai][bj][r];
        int b = m >> 11, si = m & 2047;
        if (j < 3072) {
          float bias = (j < 1024) ? bq[j] : (j < 2048) ? bk[j - 1024] : bv[j - 2048];
          v += bias;
          int jj = j & 1023, h = jj >> 6, d = jj & 63;
          size_t dst = (((size_t)(b * NHz + h) * Sz + si) << 6) + d;
          u16 hv = f2bf(v);
          if (j < 1024) Qw[dst] = hv;
          else if (j < 2048) Kw[dst] = hv;
          else Vw[dst] = hv;
        } else {
          int c = j - 3072;
          v += bs[c];
          float sig = 1.0f / (1.0f + __expf(-v));
          // fold softmax 1/sqrt(64) AND log2(e) (exp->exp2 domain) into Q scale
          Sw[(size_t)m * 128 + c] = (0.9f + 0.2f * sig) * 0.125f * LOG2E;
        }
      }
    }
  }
}

// ---------------- fallback: Q *= s (only if ws can't hold Sw) ----------------
__global__ void k_scale_q(u16* __restrict__ Qw, const float* __restrict__ Sw) {
  int tid = blockIdx.x * 256 + threadIdx.x;
  size_t base = (size_t)tid * 8;
  int bh = (int)(base >> 17);
  int si = (int)((base >> 6) & 2047);
  int d0 = (int)(base & 63);
  int b = bh >> 4, h = bh & 15;
  float s = Sw[((size_t)(b * Sz + si)) * 128 + h * 8 + (d0 >> 3)];
  u16x8 v = *(u16x8*)(Qw + base);
  #pragma unroll
  for (int j = 0; j < 8; ++j) v[j] = f2bf(bf2f(v[j]) * s);
  *(u16x8*)(Qw + base) = v;
}

// ---------------- V [bh][s][d] -> Vt [bh][d][s] ----------------
__global__ void k_trans_v(const u16* __restrict__ Vw, u16* __restrict__ Vt) {
  __shared__ u16 tile[64][65];
  int bh = blockIdx.y, s0 = blockIdx.x * 64;
  int t = threadIdx.x;
  const u16* src = Vw + ((size_t)bh * Sz + s0) * 64;
  #pragma unroll
  for (int i = 0; i < 16; ++i) {
    int idx = t + i * 256; int r = idx >> 6, c = idx & 63;
    tile[r][c] = src[r * 64 + c];
  }
  __syncthreads();
  u16* dst = Vt + (size_t)bh * 64 * Sz;
  #pragma unroll
  for (int i = 0; i < 16; ++i) {
    int idx = t + i * 256; int d = idx >> 6, ss = idx & 63;
    dst[(size_t)d * Sz + s0 + ss] = tile[ss][d];
  }
}

// ---------------- attention: staged dbuf K/V pipeline + in-lane softmax ----------------
__launch_bounds__(256)
__global__ void k_attn(const u16* __restrict__ Qw, const u16* __restrict__ Kw,
                       const u16* __restrict__ Vt, const float* __restrict__ Swp,
                       float* __restrict__ out) {
  __shared__ u16 Kl[2][64 * 64];
  __shared__ u16 Vl[2][64 * 64];
  __shared__ u16 Pl[4][32 * 64];

  int t = threadIdx.x, lane = t & 63, wave = t >> 6;
  int l15 = lane & 15, g = lane >> 4;
  int bh = blockIdx.x, b = bh >> 4, h = bh & 15;
  int q0 = blockIdx.y * 128 + wave * 32;

  const u16* Qb = Qw + (size_t)bh * Sz * 64;
  const char* Kg = (const char*)(Kw + (size_t)bh * Sz * 64);
  const char* Vg = (const char*)(Vt + (size_t)bh * 64 * Sz);
  u16* Pw = Pl[wave];
  int swp = (l15 & 7) << 4;

  int srow = t >> 3;
  int sobyte = (t & 7) << 4;

  bf16x8 qf[2][2];
  #pragma unroll
  for (int qi = 0; qi < 2; ++qi)
    #pragma unroll
    for (int ks = 0; ks < 2; ++ks)
      qf[qi][ks] = *(const bf16x8*)(Qb + (size_t)(q0 + 16 * qi + l15) * 64 + 32 * ks + 8 * g);
  if (Swp) {
    #pragma unroll
    for (int qi = 0; qi < 2; ++qi) {
      size_t m = (size_t)(b * Sz + q0 + 16 * qi + l15);
      #pragma unroll
      for (int ks = 0; ks < 2; ++ks) {
        float s = Swp[m * 128 + h * 8 + 4 * ks + g];
        bf16x8 q = qf[qi][ks];
        #pragma unroll
        for (int j = 0; j < 8; ++j) q[j] = (short)f2bf(bf2f((u16)q[j]) * s);
        qf[qi][ks] = q;
      }
    }
  }

  f32x4 o[2][4];
  #pragma unroll
  for (int qi = 0; qi < 2; ++qi)
    #pragma unroll
    for (int nt = 0; nt < 4; ++nt) { f32x4 z = {0.f,0.f,0.f,0.f}; o[qi][nt] = z; }
  float lsum[2] = {0.f, 0.f};

  #pragma unroll
  for (int c = 0; c < 2; ++c) {
    int row = c * 32 + srow;
    int sw2 = (row & 7) << 4;
    gll16(Kg + (size_t)row * 128 + (sobyte ^ sw2), (char*)Kl[0] + row * 128 + sobyte);
    gll16(Vg + (size_t)row * (Sz * 2) + (sobyte ^ sw2), (char*)Vl[0] + row * 128 + sobyte);
  }
  __syncthreads();

  int cur = 0;
  for (int kv0 = 0; kv0 < Sz; kv0 += 64) {
    if (kv0 + 64 < Sz) {
      int nxt = cur ^ 1, kvn = kv0 + 64;
      #pragma unroll
      for (int c = 0; c < 2; ++c) {
        int row = c * 32 + srow;
        int sw2 = (row & 7) << 4;
        gll16(Kg + (size_t)(kvn + row) * 128 + (sobyte ^ sw2),
              (char*)Kl[nxt] + row * 128 + sobyte);
        gll16(Vg + (size_t)row * (Sz * 2) + (size_t)kvn * 2 + (sobyte ^ sw2),
              (char*)Vl[nxt] + row * 128 + sobyte);
      }
    }
    const char* Kb = (const char*)Kl[cur];
    const char* Vb = (const char*)Vl[cur];

    f32x4 sc[2][4];
    __builtin_amdgcn_s_setprio(1);
    #pragma unroll
    for (int nt = 0; nt < 4; ++nt) {
      int row = 16 * nt + l15;
      int sw2 = (row & 7) << 4;
      bf16x8 kf0 = *(const bf16x8*)(Kb + row * 128 + ((16 * g) ^ sw2));
      bf16x8 kf1 = *(const bf16x8*)(Kb + row * 128 + ((64 + 16 * g) ^ sw2));
      #pragma unroll
      for (int qi = 0; qi < 2; ++qi) {
        f32x4 a = {0.f,0.f,0.f,0.f};
        a = __builtin_amdgcn_mfma_f32_16x16x32_bf16(kf0, qf[qi][0], a, 0, 0, 0);
        a = __builtin_amdgcn_mfma_f32_16x16x32_bf16(kf1, qf[qi][1], a, 0, 0, 0);
        sc[qi][nt] = a;
      }
    }
    __builtin_amdgcn_s_setprio(0);
    #pragma unroll
    for (int qi = 0; qi < 2; ++qi) {
      int rbase = (16 * qi + l15) * 128;
      #pragma unroll
      for (int nt = 0; nt < 4; ++nt) {
        float p0 = __builtin_amdgcn_exp2f(sc[qi][nt][0]);
        float p1 = __builtin_amdgcn_exp2f(sc[qi][nt][1]);
        float p2 = __builtin_amdgcn_exp2f(sc[qi][nt][2]);
        float p3 = __builtin_amdgcn_exp2f(sc[qi][nt][3]);
        lsum[qi] += (p0 + p1) + (p2 + p3);
        u16x4 pk;
        pk[0] = f2bfrn(p0); pk[1] = f2bfrn(p1);
        pk[2] = f2bfrn(p2); pk[3] = f2bfrn(p3);
        *(u16x4*)((char*)Pw + rbase + ((32 * nt + 8 * g) ^ swp)) = pk;
      }
    }
    __builtin_amdgcn_s_setprio(1);
    #pragma unroll
    for (int ks = 0; ks < 2; ++ks) {
      bf16x8 pa[2];
      #pragma unroll
      for (int qi = 0; qi < 2; ++qi)
        pa[qi] = *(const bf16x8*)((char*)Pw + (16 * qi + l15) * 128 + ((64 * ks + 16 * g) ^ swp));
      #pragma unroll
      for (int nt = 0; nt < 4; ++nt) {
        int row = 16 * nt + l15;
        int sw2 = (row & 7) << 4;
        bf16x8 vf = *(const bf16x8*)(Vb + row * 128 + ((64 * ks + 16 * g) ^ sw2));
        o[0][nt] = __builtin_amdgcn_mfma_f32_16x16x32_bf16(pa[0], vf, o[0][nt], 0, 0, 0);
        o[1][nt] = __builtin_amdgcn_mfma_f32_16x16x32_bf16(pa[1], vf, o[1][nt], 0, 0, 0);
      }
    }
    __builtin_amdgcn_s_setprio(0);
    __syncthreads();
    cur ^= 1;
  }

  #pragma unroll
  for (int qi = 0; qi < 2; ++qi) {
    float l = lsum[qi];
    l += __shfl_xor(l, 16);
    l += __shfl_xor(l, 32);
    lsum[qi] = 1.0f / l;
  }
  #pragma unroll
  for (int qi = 0; qi < 2; ++qi) {
    float li[4];
    #pragma unroll
    for (int r = 0; r < 4; ++r) li[r] = __shfl(lsum[qi], 4 * g + r);
    #pragma unroll
    for (int nt = 0; nt < 4; ++nt)
      #pragma unroll
      for (int r = 0; r < 4; ++r)
        out[((size_t)(b * Sz + q0 + 16 * qi + 4 * g + r)) * (NHz * HDz) +
            h * 64 + 16 * nt + l15] = o[qi][nt][r] * li[r];
  }
}

extern "C" void kernel_launch(void* const* d_in, const int* in_sizes, int n_in,
                              void* d_out, int out_size, void* d_ws, size_t ws_size,
                              hipStream_t stream) {
  const float* X  = (const float*)d_in[0];
  const float* Wq = (const float*)d_in[1];
  const float* bq = (const float*)d_in[2];
  const float* Wk = (const float*)d_in[3];
  const float* bk = (const float*)d_in[4];
  const float* Wv = (const float*)d_in[5];
  const float* bv = (const float*)d_in[6];
  const float* Ws = (const float*)d_in[7];
  const float* bs = (const float*)d_in[8];
  float* out = (float*)d_out;

  // ws: Qw | Kw | Vw | Vt (16 MB each) [+ Sw 4MB if room]
  char* ws = (char*)d_ws;
  u16* Qw = (u16*)(ws);
  u16* Kw = (u16*)(ws + (size_t)(16u << 20));
  u16* Vw = (u16*)(ws + (size_t)(32u << 20));
  u16* Vt = (u16*)(ws + (size_t)(48u << 20));

  // d_out scratch: Xb (16MB) | Wt (6.55MB) — consumed by k_gemm before attn writes.
  char* ob = (char*)d_out;
  u16* Xb   = (u16*)ob;
  u16* Wt   = (u16*)(ob + (size_t)(16u << 20));

  bool fused = ws_size >= ((size_t)(64u << 20) + (size_t)(4u << 20));
  float* Sw = fused ? (float*)(ws + (size_t)(64u << 20))
                    : (float*)(ob + (size_t)(24u << 20));  // fallback: consumed pre-attn

  k_cvt_x<<<8192, 256, 0, stream>>>(X, Xb);
  k_cvt_w<<<dim3(50, 16), 256, 0, stream>>>(Wq, Wk, Wv, Ws, Wt);
  k_gemm<<<1600, 512, 0, stream>>>(Xb, Wt, bq, bk, bv, bs, Qw, Kw, Vw, Sw);
  if (!fused) k_scale_q<<<4096, 256, 0, stream>>>(Qw, Sw);
  k_trans_v<<<dim3(32, 64), 256, 0, stream>>>(Vw, Vt);
  k_attn<<<dim3(64, 16), 256, 0, stream>>>(Qw, Kw, Vt, fused ? Sw : nullptr, out);
}